// Round 2
// baseline (1048.477 us; speedup 1.0000x reference)
//
#include <hip/hip_runtime.h>
#include <hip/hip_bf16.h>

// ---------------- problem constants ----------------
#define NB    2
#define NS    1024
#define NPTS  8192
#define NGROUP (NB*NS*4)   // 8192 groups = rows

// ---------------- ws layout (float offsets) ----------------
enum : int {
  OFF_W1   = 0,        // 64*3
  OFF_B1   = 192,      // 64
  OFF_W2   = 256,      // 128*64
  OFF_B2   = 8448,     // 128
  OFF_W3   = 8576,     // 256*128
  OFF_B3   = 41344,    // 256
  OFF_HO1  = 41600,    // 128*256
  OFF_HO1B = 74368,    // 128
  OFF_HO2  = 74496,    // 128*128
  OFF_HO2B = 90880,    // 128
  OFF_HO3  = 91008,    // 36*128
  OFF_HO3B = 95616,    // 36 (padded to 64)
  OFF_HT1  = 95680,    // 128*256
  OFF_HT1B = 128448,   // 128
  OFF_HT2  = 128576,   // 128*128
  OFF_HT2B = 144960,   // 128
  OFF_HT3  = 145088,   // 12*128
  OFF_HT3B = 146624,   // 12 (padded to 64)
  PREP_TOTAL = 146688,
  OFF_FEAT = 146688,            // 8192 * 64 * 3
  OFF_VP   = 1719552,           // 8192 * 256
  OFF_CNT  = 3816704,           // 8192 ints
  OFF_FLAG = 3824896,           // 1 int: 0 = inputs are bf16, 1 = inputs are fp32
};

struct Ptrs { const void* p[25]; };

// typed element loader (returns fp32)
template<typename T> struct LD;
template<> struct LD<float> {
  static __device__ __forceinline__ float get(const void* p, int i){ return ((const float*)p)[i]; }
};
template<> struct LD<__hip_bfloat16> {
  static __device__ __forceinline__ float get(const void* p, int i){ return __bfloat162float(((const __hip_bfloat16*)p)[i]); }
};

template<typename T>
__device__ __forceinline__ float bnscale(const void* bn, int C, int c){
  float g = LD<T>::get(bn, c);
  float v = LD<T>::get(bn, 3*C + c);
  return g / sqrtf(v + 1e-5f);
}

// ---------------- kernel -1: detect input dtype ----------------
// True bf16 weights (finite normals) never have exponent bits all-ones.
// If the buffers are actually fp32, their low-16 halves are ~uniform random
// u16s: P(no exp=0xFF pattern in 20480 random halves) ~ e^-80.
__global__ __launch_bounds__(256) void detect_kernel(const void* w2, const void* w3, int* flag){
  __shared__ int f;
  int t = threadIdx.x;
  if (t == 0) f = 0;
  __syncthreads();
  int loc = 0;
  const unsigned short* a = (const unsigned short*)w2;
  for (int i = t; i < 8192; i += 256)  loc |= ((a[i] & 0x7F80) == 0x7F80);
  const unsigned short* b = (const unsigned short*)w3;
  for (int i = t; i < 32768; i += 256) loc |= ((b[i] & 0x7F80) == 0x7F80);
  if (loc) atomicOr(&f, 1);
  __syncthreads();
  if (t == 0) flag[0] = f;
}

// ---------------- kernel 0: fold BN into weights (fp32 into ws) ----------------
template<typename T>
__global__ __launch_bounds__(256) void prep_kernel(Ptrs in, float* __restrict__ ws, int want){
  if (((const volatile int*)(ws + OFF_FLAG))[0] != want) return;
  int i = blockIdx.x*256 + threadIdx.x;
  if (i >= PREP_TOTAL) return;
  if (i < 192) { int c = i/3; float s = bnscale<T>(in.p[4],64,c);
    ws[OFF_W1+i] = LD<T>::get(in.p[3],i)*s; return; }
  i -= 192;
  if (i < 64) { float s = bnscale<T>(in.p[4],64,i);
    ws[OFF_B1+i] = LD<T>::get(in.p[4],64+i) - LD<T>::get(in.p[4],2*64+i)*s; return; }
  i -= 64;
  if (i < 8192) { int c = i>>6; float s = bnscale<T>(in.p[6],128,c);
    ws[OFF_W2+i] = LD<T>::get(in.p[5],i)*s; return; }
  i -= 8192;
  if (i < 128) { float s = bnscale<T>(in.p[6],128,i);
    ws[OFF_B2+i] = LD<T>::get(in.p[6],128+i) - LD<T>::get(in.p[6],2*128+i)*s; return; }
  i -= 128;
  if (i < 32768) { int c = i>>7; float s = bnscale<T>(in.p[8],256,c);
    ws[OFF_W3+i] = LD<T>::get(in.p[7],i)*s; return; }
  i -= 32768;
  if (i < 256) { float s = bnscale<T>(in.p[8],256,i);
    ws[OFF_B3+i] = LD<T>::get(in.p[8],256+i) - LD<T>::get(in.p[8],2*256+i)*s; return; }
  i -= 256;
  if (i < 32768) { int c = i>>8; float s = bnscale<T>(in.p[11],128,c);
    ws[OFF_HO1+i] = LD<T>::get(in.p[9],i)*s; return; }
  i -= 32768;
  if (i < 128) { float s = bnscale<T>(in.p[11],128,i);
    ws[OFF_HO1B+i] = (LD<T>::get(in.p[10],i) - LD<T>::get(in.p[11],2*128+i))*s + LD<T>::get(in.p[11],128+i); return; }
  i -= 128;
  if (i < 16384) { int c = i>>7; float s = bnscale<T>(in.p[14],128,c);
    ws[OFF_HO2+i] = LD<T>::get(in.p[12],i)*s; return; }
  i -= 16384;
  if (i < 128) { float s = bnscale<T>(in.p[14],128,i);
    ws[OFF_HO2B+i] = (LD<T>::get(in.p[13],i) - LD<T>::get(in.p[14],2*128+i))*s + LD<T>::get(in.p[14],128+i); return; }
  i -= 128;
  if (i < 4608) { ws[OFF_HO3+i] = LD<T>::get(in.p[15],i); return; }
  i -= 4608;
  if (i < 64) { ws[OFF_HO3B+i] = (i < 36) ? LD<T>::get(in.p[16],i) : 0.f; return; }
  i -= 64;
  if (i < 32768) { int c = i>>8; float s = bnscale<T>(in.p[19],128,c);
    ws[OFF_HT1+i] = LD<T>::get(in.p[17],i)*s; return; }
  i -= 32768;
  if (i < 128) { float s = bnscale<T>(in.p[19],128,i);
    ws[OFF_HT1B+i] = (LD<T>::get(in.p[18],i) - LD<T>::get(in.p[19],2*128+i))*s + LD<T>::get(in.p[19],128+i); return; }
  i -= 128;
  if (i < 16384) { int c = i>>7; float s = bnscale<T>(in.p[22],128,c);
    ws[OFF_HT2+i] = LD<T>::get(in.p[20],i)*s; return; }
  i -= 16384;
  if (i < 128) { float s = bnscale<T>(in.p[22],128,i);
    ws[OFF_HT2B+i] = (LD<T>::get(in.p[21],i) - LD<T>::get(in.p[22],2*128+i))*s + LD<T>::get(in.p[22],128+i); return; }
  i -= 128;
  if (i < 1536) { ws[OFF_HT3+i] = LD<T>::get(in.p[23],i); return; }
  i -= 1536;
  ws[OFF_HT3B+i] = (i < 12) ? LD<T>::get(in.p[24],i) : 0.f;
}

// ---------------- kernel 1: cylinder grouping ----------------
// 2048 blocks (one per (b,seed)), 4 waves = 4 depth bins. Ballot+prefix-popcount
// reproduces top_k's "first 64 valid indices in order"; fill duplicates are
// elided (they never change the later max-pool). cnt[g] = clamp(V,1,64).
template<typename T>
__global__ __launch_bounds__(256) void group_kernel(
    const void* __restrict__ seed, const void* __restrict__ pc,
    const void* __restrict__ vr, float* __restrict__ ws, int want)
{
#pragma clang fp contract(off)
  if (((const volatile int*)(ws + OFF_FLAG))[0] != want) return;
  float* feat = ws + OFF_FEAT;
  int* cnt = (int*)(ws + OFF_CNT);
  int bs = blockIdx.x;                 // 0..2047
  int b = bs >> 10;
  int wave = threadIdx.x >> 6, lane = threadIdx.x & 63;
  float sx = LD<T>::get(seed, bs*3+0), sy = LD<T>::get(seed, bs*3+1), sz = LD<T>::get(seed, bs*3+2);
  float r00=LD<T>::get(vr,bs*9+0), r01=LD<T>::get(vr,bs*9+1), r02=LD<T>::get(vr,bs*9+2);
  float r10=LD<T>::get(vr,bs*9+3), r11=LD<T>::get(vr,bs*9+4), r12=LD<T>::get(vr,bs*9+5);
  float r20=LD<T>::get(vr,bs*9+6), r21=LD<T>::get(vr,bs*9+7), r22=LD<T>::get(vr,bs*9+8);
  const float hmaxs[4] = {0.1f, 0.2f, 0.3f, 0.4f};
  float hmax = hmaxs[wave];
  int g = bs*4 + wave;
  float* fout = feat + g*192;
  int base = b*(NPTS*3);
  int count = 0;
  float p0x=0.f, p0y=0.f, p0z=0.f;
  for (int c0 = 0; c0 < NPTS && count < 64; c0 += 64) {
    int pi = base + (c0 + lane)*3;
    float e0 = LD<T>::get(pc, pi+0) - sx;
    float e1 = LD<T>::get(pc, pi+1) - sy;
    float e2 = LD<T>::get(pc, pi+2) - sz;
    float rx = e0*r00 + e1*r10 + e2*r20;
    float ry = e0*r01 + e1*r11 + e2*r21;
    float rz = e0*r02 + e1*r12 + e2*r22;
    float r2 = ry*ry + rz*rz;
    bool m = (rx > -0.2f) && (rx < hmax) && (r2 < 0.09f);
    if (c0 == 0 && lane == 0) { p0x = rx; p0y = ry; p0z = rz; }
    unsigned long long bal = __ballot(m);
    int rank = __popcll(bal & ((1ull << lane) - 1ull));
    int slot = count + rank;
    if (m && slot < 64) { fout[slot*3+0]=rx; fout[slot*3+1]=ry; fout[slot*3+2]=rz; }
    count += __popcll(bal);
  }
  if (count == 0) {
    if (lane == 0) { fout[0]=p0x; fout[1]=p0y; fout[2]=p0z; }
    count = 1;
  }
  if (lane == 0) cnt[g] = (count > 64) ? 64 : count;
}

// ---------------- kernel 2: SharedMLP + maxpool (per group, only V samples) ----------------
__global__ __launch_bounds__(256) void mlp_kernel(float* __restrict__ ws){
  __shared__ float sx[192];
  __shared__ float h1[64*64];
  __shared__ float h2[64*128];
  int g = blockIdx.x;
  int t = threadIdx.x;
  int V = ((const int*)(ws + OFF_CNT))[g];
  const float* feat = ws + OFF_FEAT + g*192;
  for (int i = t; i < V*3; i += 256) sx[i] = feat[i];
  __syncthreads();
  { // L1: 3 -> 64
    int c = t & 63, ig = t >> 6;
    const float* W1 = ws + OFF_W1 + c*3;
    float w0 = W1[0], w1 = W1[1], w2 = W1[2];
    float bb = ws[OFF_B1 + c];
    for (int i = ig; i < V; i += 4) {
      float v = bb + sx[i*3]*w0 + sx[i*3+1]*w1 + sx[i*3+2]*w2;
      h1[i*64 + c] = fmaxf(v, 0.f);
    }
  }
  __syncthreads();
  { // L2: 64 -> 128, weight row resident in VGPRs
    int c = t & 127, ih = t >> 7;
    const float* W2 = ws + OFF_W2 + c*64;
    float w[64];
#pragma unroll
    for (int k = 0; k < 16; ++k) ((float4*)w)[k] = ((const float4*)W2)[k];
    float bb = ws[OFF_B2 + c];
    for (int i = ih; i < V; i += 2) {
      float acc = bb;
#pragma unroll
      for (int k = 0; k < 64; ++k) acc += h1[i*64 + k] * w[k];
      h2[i*128 + c] = fmaxf(acc, 0.f);
    }
  }
  __syncthreads();
  { // L3: 128 -> 256 fused with max over samples (relu(h3)>=0 so 0 is identity)
    int c = t;
    const float* W3 = ws + OFF_W3 + c*128;
    float bb = ws[OFF_B3 + c];
    float m = 0.f;
    for (int i0 = 0; i0 < V; i0 += 8) {
      float part[8];
#pragma unroll
      for (int j = 0; j < 8; ++j) part[j] = bb;
      for (int kt = 0; kt < 4; ++kt) {
        float w[32];
#pragma unroll
        for (int k = 0; k < 8; ++k) ((float4*)w)[k] = ((const float4*)(W3 + kt*32))[k];
#pragma unroll
        for (int j = 0; j < 8; ++j) {
          if (i0 + j < V) {
            const float* hh = h2 + (i0+j)*128 + kt*32;
#pragma unroll
            for (int k = 0; k < 32; ++k) part[j] += hh[k]*w[k];
          }
        }
      }
#pragma unroll
      for (int j = 0; j < 8; ++j) if (i0 + j < V) m = fmaxf(m, part[j]);
    }
    ws[OFF_VP + g*256 + c] = m;
  }
}

// ---------------- kernel 3: two heads + output transpose ----------------
#define HROWS 16
template<typename OUT>
__global__ __launch_bounds__(256) void heads_kernel(float* __restrict__ ws, OUT* __restrict__ out, int want){
  if (((const volatile int*)(ws + OFF_FLAG))[0] != want) return;
  __shared__ float xa[HROWS*256];
  __shared__ float xb[HROWS*256];
  int t = threadIdx.x;
  int r0 = blockIdx.x * HROWS;
  const float* vp = ws + OFF_VP + r0*256;
  { // head layer 1: 256 -> (128|128), thread = output channel (both heads)
    int head = t >> 7, ch = t & 127;
    const float* W = ws + (head ? OFF_HT1 : OFF_HO1) + ch*256;
    float bb = ws[(head ? OFF_HT1B : OFF_HO1B) + ch];
    float acc[HROWS];
#pragma unroll
    for (int r = 0; r < HROWS; ++r) acc[r] = bb;
    for (int kt = 0; kt < 8; ++kt) {
      float w[32];
#pragma unroll
      for (int k = 0; k < 8; ++k) ((float4*)w)[k] = ((const float4*)(W + kt*32))[k];
#pragma unroll
      for (int r = 0; r < HROWS; ++r) {
        const float* x = vp + r*256 + kt*32;
#pragma unroll
        for (int k = 0; k < 32; ++k) acc[r] += x[k]*w[k];
      }
    }
#pragma unroll
    for (int r = 0; r < HROWS; ++r) xa[r*256 + t] = fmaxf(acc[r], 0.f);
  }
  __syncthreads();
  { // head layer 2: 128 -> 128 per head
    int head = t >> 7, ch = t & 127;
    const float* W = ws + (head ? OFF_HT2 : OFF_HO2) + ch*128;
    float bb = ws[(head ? OFF_HT2B : OFF_HO2B) + ch];
    float acc[HROWS];
#pragma unroll
    for (int r = 0; r < HROWS; ++r) acc[r] = bb;
    for (int kt = 0; kt < 4; ++kt) {
      float w[32];
#pragma unroll
      for (int k = 0; k < 8; ++k) ((float4*)w)[k] = ((const float4*)(W + kt*32))[k];
#pragma unroll
      for (int r = 0; r < HROWS; ++r) {
        const float* x = xa + r*256 + head*128 + kt*32;
#pragma unroll
        for (int k = 0; k < 32; ++k) acc[r] += x[k]*w[k];
      }
    }
#pragma unroll
    for (int r = 0; r < HROWS; ++r) xb[r*256 + t] = fmaxf(acc[r], 0.f);
  }
  __syncthreads();
  { // head layer 3: 128 -> 36 | 12, write transposed output (B,48,1024,4)
    for (int oi = t; oi < HROWS*48; oi += 256) {
      int row = oi / 48, och = oi - row*48;
      bool isT = och >= 36;
      int lch = isT ? (och - 36) : och;
      const float* W = ws + (isT ? OFF_HT3 : OFF_HO3) + lch*128;
      float acc = ws[(isT ? OFF_HT3B : OFF_HO3B) + lch];
      const float* x = xb + row*256 + (isT ? 128 : 0);
#pragma unroll
      for (int k = 0; k < 128; ++k) acc += x[k]*W[k];
      int gr = r0 + row;
      int b = gr >> 12, rem = gr & 4095, s = rem >> 2, d = rem & 3;
      out[((b*48 + och)*1024 + s)*4 + d] = (OUT)acc;
    }
  }
}

extern "C" void kernel_launch(void* const* d_in, const int* in_sizes, int n_in,
                              void* d_out, int out_size, void* d_ws, size_t ws_size,
                              hipStream_t stream) {
  float* ws = (float*)d_ws;
  Ptrs P;
  for (int i = 0; i < 25; ++i) P.p[i] = d_in[i];
  detect_kernel<<<1, 256, 0, stream>>>(d_in[5], d_in[7], (int*)(ws + OFF_FLAG));
  prep_kernel<__hip_bfloat16><<<PREP_TOTAL/256, 256, 0, stream>>>(P, ws, 0);
  prep_kernel<float><<<PREP_TOTAL/256, 256, 0, stream>>>(P, ws, 1);
  group_kernel<__hip_bfloat16><<<NB*NS, 256, 0, stream>>>(d_in[0], d_in[1], d_in[2], ws, 0);
  group_kernel<float><<<NB*NS, 256, 0, stream>>>(d_in[0], d_in[1], d_in[2], ws, 1);
  mlp_kernel<<<NGROUP, 256, 0, stream>>>(ws);
  heads_kernel<__hip_bfloat16><<<NGROUP/HROWS, 256, 0, stream>>>(ws, (__hip_bfloat16*)d_out, 0);
  heads_kernel<float><<<NGROUP/HROWS, 256, 0, stream>>>(ws, (float*)d_out, 1);
}

// Round 3
// 361.713 us; speedup vs baseline: 2.8986x; 2.8986x over previous
//
#include <hip/hip_runtime.h>
#include <hip/hip_bf16.h>

// ---------------- problem constants ----------------
#define NB    2
#define NS    1024
#define NPTS  8192
#define NGROUP (NB*NS*4)   // 8192 groups = rows

// ---------------- ws layout (float offsets) ----------------
enum : int {
  OFF_BW2  = 256,      // 8192 bf16 (4096 floats): W2 folded, B-fragment order
  OFF_W1Q  = 4352,     // 64 x float4 (w0,w1,w2,b) folded L1
  OFF_B2   = 8448,     // 128 f32 folded bias
  OFF_BW3  = 8576,     // 32768 bf16 (16384 floats): W3 folded, B-fragment order
  OFF_B3   = 41344,    // 256 f32 folded bias
  OFF_HO1  = 41600,    // 128*256
  OFF_HO1B = 74368,    // 128
  OFF_HO2  = 74496,    // 128*128
  OFF_HO2B = 90880,    // 128
  OFF_HO3  = 91008,    // 36*128
  OFF_HO3B = 95616,    // 36 (padded to 64)
  OFF_HT1  = 95680,    // 128*256
  OFF_HT1B = 128448,   // 128
  OFF_HT2  = 128576,   // 128*128
  OFF_HT2B = 144960,   // 128
  OFF_HT3  = 145088,   // 12*128
  OFF_HT3B = 146624,   // 12 (padded to 64)
  PREP_TOTAL = 146688,
  OFF_FEAT = 146688,            // 8192 * 64 * 3
  OFF_VP   = 1719552,           // 8192 * 256
  OFF_CNT  = 3816704,           // 8192 ints
  OFF_FLAG = 3824896,           // 1 int: 0 = inputs are bf16, 1 = inputs are fp32
};

struct Ptrs { const void* p[25]; };

typedef __attribute__((ext_vector_type(8))) short bf16x8;
typedef __attribute__((ext_vector_type(4))) float f32x4;

// typed element loader (returns fp32)
template<typename T> struct LD;
template<> struct LD<float> {
  static __device__ __forceinline__ float get(const void* p, int i){ return ((const float*)p)[i]; }
};
template<> struct LD<__hip_bfloat16> {
  static __device__ __forceinline__ float get(const void* p, int i){ return __bfloat162float(((const __hip_bfloat16*)p)[i]); }
};

template<typename T>
__device__ __forceinline__ float bnscale(const void* bn, int C, int c){
  float g = LD<T>::get(bn, c);
  float v = LD<T>::get(bn, 3*C + c);
  return g / sqrtf(v + 1e-5f);
}

__device__ __forceinline__ unsigned short f2bf(float v){
  __hip_bfloat16 hb = __float2bfloat16(v);
  return *reinterpret_cast<unsigned short*>(&hb);
}

// ---------------- kernel -1: detect input dtype ----------------
__global__ __launch_bounds__(256) void detect_kernel(const void* w2, const void* w3, int* flag){
  __shared__ int f;
  int t = threadIdx.x;
  if (t == 0) f = 0;
  __syncthreads();
  int loc = 0;
  const unsigned short* a = (const unsigned short*)w2;
  for (int i = t; i < 8192; i += 256)  loc |= ((a[i] & 0x7F80) == 0x7F80);
  const unsigned short* b = (const unsigned short*)w3;
  for (int i = t; i < 32768; i += 256) loc |= ((b[i] & 0x7F80) == 0x7F80);
  if (loc) atomicOr(&f, 1);
  __syncthreads();
  if (t == 0) flag[0] = f;
}

// ---------------- kernel 0: fold BN into weights; swizzle W2/W3 to B-frag bf16 ----------------
template<typename T>
__global__ __launch_bounds__(256) void prep_kernel(Ptrs in, float* __restrict__ ws, int want){
  if (((const volatile int*)(ws + OFF_FLAG))[0] != want) return;
  int i = blockIdx.x*256 + threadIdx.x;
  if (i >= PREP_TOTAL) return;
  if (i < 256) { int c = i>>2, d = i&3; float s = bnscale<T>(in.p[4],64,c);
    float v = (d<3) ? LD<T>::get(in.p[3], c*3+d)*s
                    : LD<T>::get(in.p[4],64+c) - LD<T>::get(in.p[4],2*64+c)*s;
    ws[OFF_W1Q+i] = v; return; }
  i -= 256;
  if (i < 8192) { // BW2[(nt*2+kt)*64+lane][j] = W2fold[n][k], n=nt*16+(lane&15), k=kt*32+(lane>>4)*8+j
    int j = i&7, f = i>>3, lane = f&63, kn = f>>6, kt = kn&1, nt = kn>>1;
    int n = nt*16 + (lane&15), k = kt*32 + ((lane>>4)<<3) + j;
    float s = bnscale<T>(in.p[6],128,n);
    ((unsigned short*)(ws + OFF_BW2))[i] = f2bf(LD<T>::get(in.p[5], n*64+k)*s); return; }
  i -= 8192;
  if (i < 32768) { // BW3[(nt*4+kt)*64+lane][j] = W3fold[n][k], n=nt*16+(lane&15), k=kt*32+(lane>>4)*8+j
    int j = i&7, f = i>>3, lane = f&63, kn = f>>6, kt = kn&3, nt = kn>>2;
    int n = nt*16 + (lane&15), k = kt*32 + ((lane>>4)<<3) + j;
    float s = bnscale<T>(in.p[8],256,n);
    ((unsigned short*)(ws + OFF_BW3))[i] = f2bf(LD<T>::get(in.p[7], n*128+k)*s); return; }
  i -= 32768;
  if (i < 128) { float s = bnscale<T>(in.p[6],128,i);
    ws[OFF_B2+i] = LD<T>::get(in.p[6],128+i) - LD<T>::get(in.p[6],2*128+i)*s; return; }
  i -= 128;
  if (i < 256) { float s = bnscale<T>(in.p[8],256,i);
    ws[OFF_B3+i] = LD<T>::get(in.p[8],256+i) - LD<T>::get(in.p[8],2*256+i)*s; return; }
  i -= 256;
  if (i < 32768) { int c = i>>8; float s = bnscale<T>(in.p[11],128,c);
    ws[OFF_HO1+i] = LD<T>::get(in.p[9],i)*s; return; }
  i -= 32768;
  if (i < 128) { float s = bnscale<T>(in.p[11],128,i);
    ws[OFF_HO1B+i] = (LD<T>::get(in.p[10],i) - LD<T>::get(in.p[11],2*128+i))*s + LD<T>::get(in.p[11],128+i); return; }
  i -= 128;
  if (i < 16384) { int c = i>>7; float s = bnscale<T>(in.p[14],128,c);
    ws[OFF_HO2+i] = LD<T>::get(in.p[12],i)*s; return; }
  i -= 16384;
  if (i < 128) { float s = bnscale<T>(in.p[14],128,i);
    ws[OFF_HO2B+i] = (LD<T>::get(in.p[13],i) - LD<T>::get(in.p[14],2*128+i))*s + LD<T>::get(in.p[14],128+i); return; }
  i -= 128;
  if (i < 4608) { ws[OFF_HO3+i] = LD<T>::get(in.p[15],i); return; }
  i -= 4608;
  if (i < 64) { ws[OFF_HO3B+i] = (i < 36) ? LD<T>::get(in.p[16],i) : 0.f; return; }
  i -= 64;
  if (i < 32768) { int c = i>>8; float s = bnscale<T>(in.p[19],128,c);
    ws[OFF_HT1+i] = LD<T>::get(in.p[17],i)*s; return; }
  i -= 32768;
  if (i < 128) { float s = bnscale<T>(in.p[19],128,i);
    ws[OFF_HT1B+i] = (LD<T>::get(in.p[18],i) - LD<T>::get(in.p[19],2*128+i))*s + LD<T>::get(in.p[19],128+i); return; }
  i -= 128;
  if (i < 16384) { int c = i>>7; float s = bnscale<T>(in.p[22],128,c);
    ws[OFF_HT2+i] = LD<T>::get(in.p[20],i)*s; return; }
  i -= 16384;
  if (i < 128) { float s = bnscale<T>(in.p[22],128,i);
    ws[OFF_HT2B+i] = (LD<T>::get(in.p[21],i) - LD<T>::get(in.p[22],2*128+i))*s + LD<T>::get(in.p[22],128+i); return; }
  i -= 128;
  if (i < 1536) { ws[OFF_HT3+i] = LD<T>::get(in.p[23],i); return; }
  i -= 1536;
  ws[OFF_HT3B+i] = (i < 12) ? LD<T>::get(in.p[24],i) : 0.f;
}

// ---------------- kernel 1: cylinder grouping (unchanged, verified R2) ----------------
template<typename T>
__global__ __launch_bounds__(256) void group_kernel(
    const void* __restrict__ seed, const void* __restrict__ pc,
    const void* __restrict__ vr, float* __restrict__ ws, int want)
{
#pragma clang fp contract(off)
  if (((const volatile int*)(ws + OFF_FLAG))[0] != want) return;
  float* feat = ws + OFF_FEAT;
  int* cnt = (int*)(ws + OFF_CNT);
  int bs = blockIdx.x;
  int b = bs >> 10;
  int wave = threadIdx.x >> 6, lane = threadIdx.x & 63;
  float sx = LD<T>::get(seed, bs*3+0), sy = LD<T>::get(seed, bs*3+1), sz = LD<T>::get(seed, bs*3+2);
  float r00=LD<T>::get(vr,bs*9+0), r01=LD<T>::get(vr,bs*9+1), r02=LD<T>::get(vr,bs*9+2);
  float r10=LD<T>::get(vr,bs*9+3), r11=LD<T>::get(vr,bs*9+4), r12=LD<T>::get(vr,bs*9+5);
  float r20=LD<T>::get(vr,bs*9+6), r21=LD<T>::get(vr,bs*9+7), r22=LD<T>::get(vr,bs*9+8);
  const float hmaxs[4] = {0.1f, 0.2f, 0.3f, 0.4f};
  float hmax = hmaxs[wave];
  int g = bs*4 + wave;
  float* fout = feat + g*192;
  int base = b*(NPTS*3);
  int count = 0;
  float p0x=0.f, p0y=0.f, p0z=0.f;
  for (int c0 = 0; c0 < NPTS && count < 64; c0 += 64) {
    int pi = base + (c0 + lane)*3;
    float e0 = LD<T>::get(pc, pi+0) - sx;
    float e1 = LD<T>::get(pc, pi+1) - sy;
    float e2 = LD<T>::get(pc, pi+2) - sz;
    float rx = e0*r00 + e1*r10 + e2*r20;
    float ry = e0*r01 + e1*r11 + e2*r21;
    float rz = e0*r02 + e1*r12 + e2*r22;
    float r2 = ry*ry + rz*rz;
    bool m = (rx > -0.2f) && (rx < hmax) && (r2 < 0.09f);
    if (c0 == 0 && lane == 0) { p0x = rx; p0y = ry; p0z = rz; }
    unsigned long long bal = __ballot(m);
    int rank = __popcll(bal & ((1ull << lane) - 1ull));
    int slot = count + rank;
    if (m && slot < 64) { fout[slot*3+0]=rx; fout[slot*3+1]=ry; fout[slot*3+2]=rz; }
    count += __popcll(bal);
  }
  if (count == 0) {
    if (lane == 0) { fout[0]=p0x; fout[1]=p0y; fout[2]=p0z; }
    count = 1;
  }
  if (lane == 0) cnt[g] = (count > 64) ? 64 : count;
}

// ---------------- kernel 2: SharedMLP + maxpool via bf16 MFMA ----------------
// block = 4 waves = 2 groups; each wave owns one N-half of its group.
// L1 (K=3) on VALU straight into A-frag registers; h2 through LDS (C->A layout);
// W2/W3 read as pre-swizzled bf16 B-frags from L2; maxpool fused in L3 epilogue.
__global__ __launch_bounds__(256) void mlp_kernel(float* __restrict__ ws){
  __shared__ unsigned short h2s[2][64*136];  // padded row: 136 shorts = 272 B
  __shared__ float w1q[4][256];              // replicated per quad
  const int t = threadIdx.x;
  const int wave = t >> 6, lane = t & 63;
  const int quad = lane >> 4, l15 = lane & 15;
  const int grp = wave >> 1, nhalf = wave & 1;
  const int g = blockIdx.x*2 + grp;
  for (int i = t; i < 1024; i += 256) w1q[i>>8][i&255] = ws[OFF_W1Q + (i&255)];
  const int V = ((const int*)(ws + OFF_CNT))[g];
  const float* feat = ws + OFF_FEAT + g*192;
  __syncthreads();
  // ---- L1: h1 A-frags in regs. lane -> (m = mt*16+l15, k = kt*32+quad*8+j) bijection ----
  bf16x8 a1[4][2];
  const float* wq = w1q[quad];
#pragma unroll
  for (int mt = 0; mt < 4; ++mt) {
    const int m = mt*16 + l15;
    const float x0 = feat[m*3+0], x1 = feat[m*3+1], x2 = feat[m*3+2];
#pragma unroll
    for (int kt = 0; kt < 2; ++kt) {
      const int c0 = kt*32 + quad*8;
#pragma unroll
      for (int j = 0; j < 8; ++j) {
        const float* w = wq + (c0+j)*4;
        a1[mt][kt][j] = (short)f2bf(fmaxf(w[3] + x0*w[0] + x1*w[1] + x2*w[2], 0.f));
      }
    }
  }
  // ---- L2: 64x128x64 GEMM (this wave: N-half 64) ----
  unsigned short* h2 = h2s[grp];
  const bf16x8* BW2 = (const bf16x8*)(ws + OFF_BW2);
#pragma unroll
  for (int nt4 = 0; nt4 < 4; ++nt4) {
    const int nt = nhalf*4 + nt4;
    const int n = nt*16 + l15;
    const float bias = ws[OFF_B2 + n];
    f32x4 acc[4];
#pragma unroll
    for (int mt = 0; mt < 4; ++mt) acc[mt] = (f32x4){bias, bias, bias, bias};
#pragma unroll
    for (int kt = 0; kt < 2; ++kt) {
      const bf16x8 b = BW2[(nt*2+kt)*64 + lane];
#pragma unroll
      for (int mt = 0; mt < 4; ++mt)
        acc[mt] = __builtin_amdgcn_mfma_f32_16x16x32_bf16(a1[mt][kt], b, acc[mt], 0, 0, 0);
    }
#pragma unroll
    for (int mt = 0; mt < 4; ++mt)
#pragma unroll
      for (int jj = 0; jj < 4; ++jj) {
        const int m = mt*16 + quad*4 + jj;           // C layout: row=quad*4+reg, col=l15
        h2[m*136 + n] = f2bf(fmaxf(acc[mt][jj], 0.f));
      }
  }
  __syncthreads();
  // ---- L3: 64x256x128 GEMM (this wave: N-half 128) + fused relu/mask/maxpool ----
  bf16x8 a2[4][4];
#pragma unroll
  for (int mt = 0; mt < 4; ++mt)
#pragma unroll
    for (int kt = 0; kt < 4; ++kt)
      a2[mt][kt] = *(const bf16x8*)&h2[(mt*16 + l15)*136 + kt*32 + quad*8];
  const bf16x8* BW3 = (const bf16x8*)(ws + OFF_BW3);
  float vpv[8];
#pragma unroll
  for (int nt8 = 0; nt8 < 8; ++nt8) {
    const int nt = nhalf*8 + nt8;
    const int n = nt*16 + l15;
    const float bias = ws[OFF_B3 + n];
    f32x4 acc[4];
#pragma unroll
    for (int mt = 0; mt < 4; ++mt) acc[mt] = (f32x4){bias, bias, bias, bias};
#pragma unroll
    for (int kt = 0; kt < 4; ++kt) {
      const bf16x8 b = BW3[(nt*4+kt)*64 + lane];
#pragma unroll
      for (int mt = 0; mt < 4; ++mt)
        acc[mt] = __builtin_amdgcn_mfma_f32_16x16x32_bf16(a2[mt][kt], b, acc[mt], 0, 0, 0);
    }
    float mx = 0.f;   // relu >= 0 and V >= 1 so 0 is a safe identity
#pragma unroll
    for (int mt = 0; mt < 4; ++mt)
#pragma unroll
      for (int jj = 0; jj < 4; ++jj) {
        const int row = mt*16 + quad*4 + jj;
        const float v = fmaxf(acc[mt][jj], 0.f);
        mx = (row < V) ? fmaxf(mx, v) : mx;
      }
    mx = fmaxf(mx, __shfl_xor(mx, 16, 64));
    mx = fmaxf(mx, __shfl_xor(mx, 32, 64));
    vpv[nt8] = mx;
  }
  if (quad == 0) {
    float* vp = ws + OFF_VP + g*256 + nhalf*128;
#pragma unroll
    for (int nt8 = 0; nt8 < 8; ++nt8) vp[nt8*16 + l15] = vpv[nt8];
  }
}

// ---------------- kernel 3: two heads + output transpose ----------------
#define HROWS 16
template<typename OUT>
__global__ __launch_bounds__(256) void heads_kernel(float* __restrict__ ws, OUT* __restrict__ out, int want){
  if (((const volatile int*)(ws + OFF_FLAG))[0] != want) return;
  __shared__ float xa[HROWS*256];
  __shared__ float xb[HROWS*256];
  int t = threadIdx.x;
  int r0 = blockIdx.x * HROWS;
  const float* vp = ws + OFF_VP + r0*256;
  { // head layer 1: 256 -> (128|128)
    int head = t >> 7, ch = t & 127;
    const float* W = ws + (head ? OFF_HT1 : OFF_HO1) + ch*256;
    float bb = ws[(head ? OFF_HT1B : OFF_HO1B) + ch];
    float acc[HROWS];
#pragma unroll
    for (int r = 0; r < HROWS; ++r) acc[r] = bb;
    for (int kt = 0; kt < 8; ++kt) {
      float w[32];
#pragma unroll
      for (int k = 0; k < 8; ++k) ((float4*)w)[k] = ((const float4*)(W + kt*32))[k];
#pragma unroll
      for (int r = 0; r < HROWS; ++r) {
        const float* x = vp + r*256 + kt*32;
#pragma unroll
        for (int k = 0; k < 32; ++k) acc[r] += x[k]*w[k];
      }
    }
#pragma unroll
    for (int r = 0; r < HROWS; ++r) xa[r*256 + t] = fmaxf(acc[r], 0.f);
  }
  __syncthreads();
  { // head layer 2: 128 -> 128 per head
    int head = t >> 7, ch = t & 127;
    const float* W = ws + (head ? OFF_HT2 : OFF_HO2) + ch*128;
    float bb = ws[(head ? OFF_HT2B : OFF_HO2B) + ch];
    float acc[HROWS];
#pragma unroll
    for (int r = 0; r < HROWS; ++r) acc[r] = bb;
    for (int kt = 0; kt < 4; ++kt) {
      float w[32];
#pragma unroll
      for (int k = 0; k < 8; ++k) ((float4*)w)[k] = ((const float4*)(W + kt*32))[k];
#pragma unroll
      for (int r = 0; r < HROWS; ++r) {
        const float* x = xa + r*256 + head*128 + kt*32;
#pragma unroll
        for (int k = 0; k < 32; ++k) acc[r] += x[k]*w[k];
      }
    }
#pragma unroll
    for (int r = 0; r < HROWS; ++r) xb[r*256 + t] = fmaxf(acc[r], 0.f);
  }
  __syncthreads();
  { // head layer 3: 128 -> 36 | 12, transposed write (B,48,1024,4)
    for (int oi = t; oi < HROWS*48; oi += 256) {
      int row = oi / 48, och = oi - row*48;
      bool isT = och >= 36;
      int lch = isT ? (och - 36) : och;
      const float* W = ws + (isT ? OFF_HT3 : OFF_HO3) + lch*128;
      float acc = ws[(isT ? OFF_HT3B : OFF_HO3B) + lch];
      const float* x = xb + row*256 + (isT ? 128 : 0);
#pragma unroll
      for (int k = 0; k < 128; ++k) acc += x[k]*W[k];
      int gr = r0 + row;
      int b = gr >> 12, rem = gr & 4095, s = rem >> 2, d = rem & 3;
      out[((b*48 + och)*1024 + s)*4 + d] = (OUT)acc;
    }
  }
}

extern "C" void kernel_launch(void* const* d_in, const int* in_sizes, int n_in,
                              void* d_out, int out_size, void* d_ws, size_t ws_size,
                              hipStream_t stream) {
  float* ws = (float*)d_ws;
  Ptrs P;
  for (int i = 0; i < 25; ++i) P.p[i] = d_in[i];
  detect_kernel<<<1, 256, 0, stream>>>(d_in[5], d_in[7], (int*)(ws + OFF_FLAG));
  prep_kernel<__hip_bfloat16><<<PREP_TOTAL/256, 256, 0, stream>>>(P, ws, 0);
  prep_kernel<float><<<PREP_TOTAL/256, 256, 0, stream>>>(P, ws, 1);
  group_kernel<__hip_bfloat16><<<NB*NS, 256, 0, stream>>>(d_in[0], d_in[1], d_in[2], ws, 0);
  group_kernel<float><<<NB*NS, 256, 0, stream>>>(d_in[0], d_in[1], d_in[2], ws, 1);
  mlp_kernel<<<NGROUP/2, 256, 0, stream>>>(ws);
  heads_kernel<__hip_bfloat16><<<NGROUP/HROWS, 256, 0, stream>>>(ws, (__hip_bfloat16*)d_out, 0);
  heads_kernel<float><<<NGROUP/HROWS, 256, 0, stream>>>(ws, (float*)d_out, 1);
}

// Round 4
// 240.395 us; speedup vs baseline: 4.3615x; 1.5047x over previous
//
#include <hip/hip_runtime.h>
#include <hip/hip_bf16.h>

// ---------------- problem constants ----------------
#define NB    2
#define NS    1024
#define NPTS  8192
#define NGROUP (NB*NS*4)   // 8192 groups = rows

// ---------------- ws layout (float offsets) ----------------
enum : int {
  OFF_BW2  = 256,      // 8192 bf16: W2 folded, B-frag order
  OFF_W1Q  = 4352,     // 64 x float4 (w0,w1,w2,b) folded L1
  OFF_B2   = 8448,     // 128 f32
  OFF_BW3  = 8576,     // 32768 bf16: W3 folded, B-frag order
  OFF_B3   = 41344,    // 256 f32
  OFF_HB1  = 41600,    // 65536 bf16: combined head L1 (256x256), B-frag order
  OFF_HB1B = 74368,    // 256 f32
  OFF_HB2  = 74624,    // 65536 bf16: combined head L2 (256x256 block-diag)
  OFF_HB2B = 107392,   // 256 f32
  OFF_HB3  = 107648,   // 16384 bf16: combined head L3 (64x256 block-struct)
  OFF_HB3B = 115840,   // 64 f32
  PREP_TOTAL = 189632, // work items in prep
  OFF_FEAT = 146688,            // 8192 * 64 * 3
  OFF_VP   = 1719552,           // 8192 * 256
  OFF_CNT  = 3816704,           // 8192 ints
  OFF_FLAG = 3824896,           // 1 int: 0 = bf16 inputs, 1 = fp32 inputs
};

struct Ptrs { const void* p[25]; };

typedef __attribute__((ext_vector_type(8))) short bf16x8;
typedef __attribute__((ext_vector_type(4))) float f32x4;

template<typename T> struct LD;
template<> struct LD<float> {
  static __device__ __forceinline__ float get(const void* p, int i){ return ((const float*)p)[i]; }
};
template<> struct LD<__hip_bfloat16> {
  static __device__ __forceinline__ float get(const void* p, int i){ return __bfloat162float(((const __hip_bfloat16*)p)[i]); }
};

template<typename T>
__device__ __forceinline__ float bnscale(const void* bn, int C, int c){
  float g = LD<T>::get(bn, c);
  float v = LD<T>::get(bn, 3*C + c);
  return g / sqrtf(v + 1e-5f);
}

__device__ __forceinline__ unsigned short f2bf(float v){
  __hip_bfloat16 hb = __float2bfloat16(v);
  return *reinterpret_cast<unsigned short*>(&hb);
}

// ---------------- kernel -1: detect input dtype ----------------
__global__ __launch_bounds__(256) void detect_kernel(const void* w2, const void* w3, int* flag){
  __shared__ int f;
  int t = threadIdx.x;
  if (t == 0) f = 0;
  __syncthreads();
  int loc = 0;
  const unsigned short* a = (const unsigned short*)w2;
  for (int i = t; i < 8192; i += 256)  loc |= ((a[i] & 0x7F80) == 0x7F80);
  const unsigned short* b = (const unsigned short*)w3;
  for (int i = t; i < 32768; i += 256) loc |= ((b[i] & 0x7F80) == 0x7F80);
  if (loc) atomicOr(&f, 1);
  __syncthreads();
  if (t == 0) flag[0] = f;
}

// ---------------- kernel 0: fold BN; swizzle all GEMM weights to bf16 B-frags ----------------
// B-frag convention (16x16x32): frag id = nt*KT+kt; element [lane][j] = W[n][k],
// n = nt*16 + (lane&15), k = kt*32 + (lane>>4)*8 + j.
template<typename T>
__global__ __launch_bounds__(256) void prep_kernel(Ptrs in, float* __restrict__ ws, int want){
  if (((const volatile int*)(ws + OFF_FLAG))[0] != want) return;
  int i = blockIdx.x*256 + threadIdx.x;
  if (i >= PREP_TOTAL) return;
  if (i < 256) { int c = i>>2, d = i&3; float s = bnscale<T>(in.p[4],64,c);
    float v = (d<3) ? LD<T>::get(in.p[3], c*3+d)*s
                    : LD<T>::get(in.p[4],64+c) - LD<T>::get(in.p[4],2*64+c)*s;
    ws[OFF_W1Q+i] = v; return; }
  i -= 256;
  if (i < 8192) { // BW2: 128x64, KT=2
    int j = i&7, f = i>>3, lane = f&63, kn = f>>6, kt = kn&1, nt = kn>>1;
    int n = nt*16 + (lane&15), k = kt*32 + ((lane>>4)<<3) + j;
    float s = bnscale<T>(in.p[6],128,n);
    ((unsigned short*)(ws + OFF_BW2))[i] = f2bf(LD<T>::get(in.p[5], n*64+k)*s); return; }
  i -= 8192;
  if (i < 32768) { // BW3: 256x128, KT=4
    int j = i&7, f = i>>3, lane = f&63, kn = f>>6, kt = kn&3, nt = kn>>2;
    int n = nt*16 + (lane&15), k = kt*32 + ((lane>>4)<<3) + j;
    float s = bnscale<T>(in.p[8],256,n);
    ((unsigned short*)(ws + OFF_BW3))[i] = f2bf(LD<T>::get(in.p[7], n*128+k)*s); return; }
  i -= 32768;
  if (i < 128) { float s = bnscale<T>(in.p[6],128,i);
    ws[OFF_B2+i] = LD<T>::get(in.p[6],128+i) - LD<T>::get(in.p[6],2*128+i)*s; return; }
  i -= 128;
  if (i < 256) { float s = bnscale<T>(in.p[8],256,i);
    ws[OFF_B3+i] = LD<T>::get(in.p[8],256+i) - LD<T>::get(in.p[8],2*256+i)*s; return; }
  i -= 256;
  if (i < 65536) { // HB1: combined 256x256, KT=8 (O head rows 0..127, T head 128..255)
    int j = i&7, f = i>>3, lane = f&63, kn = f>>6, kt = kn&7, nt = kn>>3;
    int n = nt*16 + (lane&15), k = kt*32 + ((lane>>4)<<3) + j;
    float v;
    if (n < 128) v = LD<T>::get(in.p[9],  n*256+k)       * bnscale<T>(in.p[11],128,n);
    else         v = LD<T>::get(in.p[17], (n-128)*256+k) * bnscale<T>(in.p[19],128,n-128);
    ((unsigned short*)(ws + OFF_HB1))[i] = f2bf(v); return; }
  i -= 65536;
  if (i < 256) { int n = i; float v;
    if (n < 128) { float s = bnscale<T>(in.p[11],128,n);
      v = (LD<T>::get(in.p[10],n) - LD<T>::get(in.p[11],2*128+n))*s + LD<T>::get(in.p[11],128+n); }
    else { int m = n-128; float s = bnscale<T>(in.p[19],128,m);
      v = (LD<T>::get(in.p[18],m) - LD<T>::get(in.p[19],2*128+m))*s + LD<T>::get(in.p[19],128+m); }
    ws[OFF_HB1B+n] = v; return; }
  i -= 256;
  if (i < 65536) { // HB2: 256x256 block-diagonal
    int j = i&7, f = i>>3, lane = f&63, kn = f>>6, kt = kn&7, nt = kn>>3;
    int n = nt*16 + (lane&15), k = kt*32 + ((lane>>4)<<3) + j;
    float v = 0.f;
    if (n < 128) { if (k < 128)  v = LD<T>::get(in.p[12], n*128+k)            * bnscale<T>(in.p[14],128,n); }
    else         { if (k >= 128) v = LD<T>::get(in.p[20], (n-128)*128+(k-128)) * bnscale<T>(in.p[22],128,n-128); }
    ((unsigned short*)(ws + OFF_HB2))[i] = f2bf(v); return; }
  i -= 65536;
  if (i < 256) { int n = i; float v;
    if (n < 128) { float s = bnscale<T>(in.p[14],128,n);
      v = (LD<T>::get(in.p[13],n) - LD<T>::get(in.p[14],2*128+n))*s + LD<T>::get(in.p[14],128+n); }
    else { int m = n-128; float s = bnscale<T>(in.p[22],128,m);
      v = (LD<T>::get(in.p[21],m) - LD<T>::get(in.p[22],2*128+m))*s + LD<T>::get(in.p[22],128+m); }
    ws[OFF_HB2B+n] = v; return; }
  i -= 256;
  if (i < 16384) { // HB3: 64x256, rows 0..35 = O-L3 (k<128), 36..47 = T-L3 (k>=128)
    int j = i&7, f = i>>3, lane = f&63, kn = f>>6, kt = kn&7, nt = kn>>3;
    int n = nt*16 + (lane&15), k = kt*32 + ((lane>>4)<<3) + j;
    float v = 0.f;
    if (n < 36)      { if (k < 128)  v = LD<T>::get(in.p[15], n*128+k); }
    else if (n < 48) { if (k >= 128) v = LD<T>::get(in.p[23], (n-36)*128+(k-128)); }
    ((unsigned short*)(ws + OFF_HB3))[i] = f2bf(v); return; }
  i -= 16384;
  { int n = i; float v = 0.f;
    if (n < 36) v = LD<T>::get(in.p[16], n);
    else if (n < 48) v = LD<T>::get(in.p[24], n-36);
    ws[OFF_HB3B+n] = v; }
}

// ---------------- kernel 1: cylinder grouping with shared rot_rel staging ----------------
// All 4 depth bins share identical rot_rel; compute once per point into LDS SoA,
// then each wave runs its ballot scan (identical fp32 values => identical masks).
template<typename T>
__global__ __launch_bounds__(256) void group_kernel(
    const void* __restrict__ seed, const void* __restrict__ pc,
    const void* __restrict__ vr, float* __restrict__ ws, int want)
{
#pragma clang fp contract(off)
  if (((const volatile int*)(ws + OFF_FLAG))[0] != want) return;
  float* feat = ws + OFF_FEAT;
  int* cnt = (int*)(ws + OFF_CNT);
  __shared__ float rxs[256], rys[256], rzs[256];
  int bs = blockIdx.x;
  int b = bs >> 10;
  int t = threadIdx.x;
  int wave = t >> 6, lane = t & 63;
  float sx = LD<T>::get(seed, bs*3+0), sy = LD<T>::get(seed, bs*3+1), sz = LD<T>::get(seed, bs*3+2);
  float r00=LD<T>::get(vr,bs*9+0), r01=LD<T>::get(vr,bs*9+1), r02=LD<T>::get(vr,bs*9+2);
  float r10=LD<T>::get(vr,bs*9+3), r11=LD<T>::get(vr,bs*9+4), r12=LD<T>::get(vr,bs*9+5);
  float r20=LD<T>::get(vr,bs*9+6), r21=LD<T>::get(vr,bs*9+7), r22=LD<T>::get(vr,bs*9+8);
  const float hmaxs[4] = {0.1f, 0.2f, 0.3f, 0.4f};
  float hmax = hmaxs[wave];
  int g = bs*4 + wave;
  float* fout = feat + g*192;
  int base = b*(NPTS*3);
  int count = 0;
  float p0x=0.f, p0y=0.f, p0z=0.f;
  for (int c0 = 0; c0 < NPTS; c0 += 256) {
    __syncthreads();
    { int pi = base + (c0 + t)*3;
      float e0 = LD<T>::get(pc, pi+0) - sx;
      float e1 = LD<T>::get(pc, pi+1) - sy;
      float e2 = LD<T>::get(pc, pi+2) - sz;
      rxs[t] = e0*r00 + e1*r10 + e2*r20;
      rys[t] = e0*r01 + e1*r11 + e2*r21;
      rzs[t] = e0*r02 + e1*r12 + e2*r22; }
    __syncthreads();
    if (count < 64) {   // wave-uniform
      for (int sub = 0; sub < 4; ++sub) {
        int idx = sub*64 + lane;
        float rx = rxs[idx], ry = rys[idx], rz = rzs[idx];
        float r2 = ry*ry + rz*rz;
        bool m = (rx > -0.2f) && (rx < hmax) && (r2 < 0.09f);
        unsigned long long bal = __ballot(m);
        int rank = __popcll(bal & ((1ull << lane) - 1ull));
        int slot = count + rank;
        if (m && slot < 64) { fout[slot*3+0]=rx; fout[slot*3+1]=ry; fout[slot*3+2]=rz; }
        count += __popcll(bal);
      }
    }
    if (c0 == 0) { p0x = rxs[0]; p0y = rys[0]; p0z = rzs[0]; }
  }
  if (count == 0) {
    if (lane == 0) { fout[0]=p0x; fout[1]=p0y; fout[2]=p0z; }
    count = 1;
  }
  if (lane == 0) cnt[g] = (count > 64) ? 64 : count;
}

// ---------------- kernel 2: SharedMLP + maxpool via bf16 MFMA (verified R3) ----------------
__global__ __launch_bounds__(256) void mlp_kernel(float* __restrict__ ws){
  __shared__ unsigned short h2s[2][64*136];
  __shared__ float w1q[4][256];
  const int t = threadIdx.x;
  const int wave = t >> 6, lane = t & 63;
  const int quad = lane >> 4, l15 = lane & 15;
  const int grp = wave >> 1, nhalf = wave & 1;
  const int g = blockIdx.x*2 + grp;
  for (int i = t; i < 1024; i += 256) w1q[i>>8][i&255] = ws[OFF_W1Q + (i&255)];
  const int V = ((const int*)(ws + OFF_CNT))[g];
  const float* feat = ws + OFF_FEAT + g*192;
  __syncthreads();
  bf16x8 a1[4][2];
  const float* wq = w1q[quad];
#pragma unroll
  for (int mt = 0; mt < 4; ++mt) {
    const int m = mt*16 + l15;
    const float x0 = feat[m*3+0], x1 = feat[m*3+1], x2 = feat[m*3+2];
#pragma unroll
    for (int kt = 0; kt < 2; ++kt) {
      const int c0 = kt*32 + quad*8;
#pragma unroll
      for (int j = 0; j < 8; ++j) {
        const float* w = wq + (c0+j)*4;
        a1[mt][kt][j] = (short)f2bf(fmaxf(w[3] + x0*w[0] + x1*w[1] + x2*w[2], 0.f));
      }
    }
  }
  unsigned short* h2 = h2s[grp];
  const bf16x8* BW2 = (const bf16x8*)(ws + OFF_BW2);
#pragma unroll
  for (int nt4 = 0; nt4 < 4; ++nt4) {
    const int nt = nhalf*4 + nt4;
    const int n = nt*16 + l15;
    const float bias = ws[OFF_B2 + n];
    f32x4 acc[4];
#pragma unroll
    for (int mt = 0; mt < 4; ++mt) acc[mt] = (f32x4){bias, bias, bias, bias};
#pragma unroll
    for (int kt = 0; kt < 2; ++kt) {
      const bf16x8 b = BW2[(nt*2+kt)*64 + lane];
#pragma unroll
      for (int mt = 0; mt < 4; ++mt)
        acc[mt] = __builtin_amdgcn_mfma_f32_16x16x32_bf16(a1[mt][kt], b, acc[mt], 0, 0, 0);
    }
#pragma unroll
    for (int mt = 0; mt < 4; ++mt)
#pragma unroll
      for (int jj = 0; jj < 4; ++jj) {
        const int m = mt*16 + quad*4 + jj;
        h2[m*136 + n] = f2bf(fmaxf(acc[mt][jj], 0.f));
      }
  }
  __syncthreads();
  bf16x8 a2[4][4];
#pragma unroll
  for (int mt = 0; mt < 4; ++mt)
#pragma unroll
    for (int kt = 0; kt < 4; ++kt)
      a2[mt][kt] = *(const bf16x8*)&h2[(mt*16 + l15)*136 + kt*32 + quad*8];
  const bf16x8* BW3 = (const bf16x8*)(ws + OFF_BW3);
  float vpv[8];
#pragma unroll
  for (int nt8 = 0; nt8 < 8; ++nt8) {
    const int nt = nhalf*8 + nt8;
    const int n = nt*16 + l15;
    const float bias = ws[OFF_B3 + n];
    f32x4 acc[4];
#pragma unroll
    for (int mt = 0; mt < 4; ++mt) acc[mt] = (f32x4){bias, bias, bias, bias};
#pragma unroll
    for (int kt = 0; kt < 4; ++kt) {
      const bf16x8 b = BW3[(nt*4+kt)*64 + lane];
#pragma unroll
      for (int mt = 0; mt < 4; ++mt)
        acc[mt] = __builtin_amdgcn_mfma_f32_16x16x32_bf16(a2[mt][kt], b, acc[mt], 0, 0, 0);
    }
    float mx = 0.f;
#pragma unroll
    for (int mt = 0; mt < 4; ++mt)
#pragma unroll
      for (int jj = 0; jj < 4; ++jj) {
        const int row = mt*16 + quad*4 + jj;
        const float v = fmaxf(acc[mt][jj], 0.f);
        mx = (row < V) ? fmaxf(mx, v) : mx;
      }
    mx = fmaxf(mx, __shfl_xor(mx, 16, 64));
    mx = fmaxf(mx, __shfl_xor(mx, 32, 64));
    vpv[nt8] = mx;
  }
  if (quad == 0) {
    float* vp = ws + OFF_VP + g*256 + nhalf*128;
#pragma unroll
    for (int nt8 = 0; nt8 < 8; ++nt8) vp[nt8*16 + l15] = vpv[nt8];
  }
}

// ---------------- kernel 3: heads via bf16 MFMA, fused transpose write ----------------
// 16 rows/block, 512 blocks, 4 waves split N (64 each for L1/L2, 16 for L3).
#define YSTRIDE 264   // shorts; 132 dwords, 132%32=4 -> 2-way (free) A-frag reads
template<typename OUT>
__global__ __launch_bounds__(256) void heads_kernel(float* __restrict__ ws, OUT* __restrict__ out, int want){
  if (((const volatile int*)(ws + OFF_FLAG))[0] != want) return;
  __shared__ unsigned short y[16*YSTRIDE];
  const int t = threadIdx.x;
  const int wave = t >> 6, lane = t & 63;
  const int quad = lane >> 4, l15 = lane & 15;
  const int r0 = blockIdx.x * 16;
  // A1 frags from vp (fp32 -> bf16)
  bf16x8 a[8];
  const float* vp = ws + OFF_VP + (r0 + l15)*256;
#pragma unroll
  for (int kt = 0; kt < 8; ++kt) {
    const float4* v4 = (const float4*)(vp + kt*32 + quad*8);
    float4 u0 = v4[0], u1 = v4[1];
    a[kt][0]=(short)f2bf(u0.x); a[kt][1]=(short)f2bf(u0.y); a[kt][2]=(short)f2bf(u0.z); a[kt][3]=(short)f2bf(u0.w);
    a[kt][4]=(short)f2bf(u1.x); a[kt][5]=(short)f2bf(u1.y); a[kt][6]=(short)f2bf(u1.z); a[kt][7]=(short)f2bf(u1.w);
  }
  const bf16x8* HB1 = (const bf16x8*)(ws + OFF_HB1);
#pragma unroll
  for (int nt4 = 0; nt4 < 4; ++nt4) {
    const int nt = wave*4 + nt4;
    const int n = nt*16 + l15;
    const float bias = ws[OFF_HB1B + n];
    f32x4 acc = (f32x4){bias, bias, bias, bias};
#pragma unroll
    for (int kt = 0; kt < 8; ++kt)
      acc = __builtin_amdgcn_mfma_f32_16x16x32_bf16(a[kt], HB1[(nt*8+kt)*64 + lane], acc, 0, 0, 0);
#pragma unroll
    for (int jj = 0; jj < 4; ++jj)
      y[(quad*4+jj)*YSTRIDE + n] = f2bf(fmaxf(acc[jj], 0.f));
  }
  __syncthreads();
#pragma unroll
  for (int kt = 0; kt < 8; ++kt)
    a[kt] = *(const bf16x8*)&y[l15*YSTRIDE + kt*32 + quad*8];
  __syncthreads();
  const bf16x8* HB2 = (const bf16x8*)(ws + OFF_HB2);
#pragma unroll
  for (int nt4 = 0; nt4 < 4; ++nt4) {
    const int nt = wave*4 + nt4;
    const int n = nt*16 + l15;
    const float bias = ws[OFF_HB2B + n];
    f32x4 acc = (f32x4){bias, bias, bias, bias};
#pragma unroll
    for (int kt = 0; kt < 8; ++kt)
      acc = __builtin_amdgcn_mfma_f32_16x16x32_bf16(a[kt], HB2[(nt*8+kt)*64 + lane], acc, 0, 0, 0);
#pragma unroll
    for (int jj = 0; jj < 4; ++jj)
      y[(quad*4+jj)*YSTRIDE + n] = f2bf(fmaxf(acc[jj], 0.f));
  }
  __syncthreads();
#pragma unroll
  for (int kt = 0; kt < 8; ++kt)
    a[kt] = *(const bf16x8*)&y[l15*YSTRIDE + kt*32 + quad*8];
  const bf16x8* HB3 = (const bf16x8*)(ws + OFF_HB3);
  {
    const int n = wave*16 + l15;   // output channel 0..63 (>=48 padded)
    const float bias = ws[OFF_HB3B + n];
    f32x4 acc = (f32x4){bias, bias, bias, bias};
#pragma unroll
    for (int kt = 0; kt < 8; ++kt)
      acc = __builtin_amdgcn_mfma_f32_16x16x32_bf16(a[kt], HB3[(wave*8+kt)*64 + lane], acc, 0, 0, 0);
    if (n < 48) {
#pragma unroll
      for (int jj = 0; jj < 4; ++jj) {
        const int gr = r0 + quad*4 + jj;
        const int b = gr >> 12, rem = gr & 4095, s = rem >> 2, d = rem & 3;
        out[((b*48 + n)*1024 + s)*4 + d] = (OUT)acc[jj];
      }
    }
  }
}

extern "C" void kernel_launch(void* const* d_in, const int* in_sizes, int n_in,
                              void* d_out, int out_size, void* d_ws, size_t ws_size,
                              hipStream_t stream) {
  float* ws = (float*)d_ws;
  Ptrs P;
  for (int i = 0; i < 25; ++i) P.p[i] = d_in[i];
  detect_kernel<<<1, 256, 0, stream>>>(d_in[5], d_in[7], (int*)(ws + OFF_FLAG));
  prep_kernel<__hip_bfloat16><<<(PREP_TOTAL+255)/256, 256, 0, stream>>>(P, ws, 0);
  prep_kernel<float><<<(PREP_TOTAL+255)/256, 256, 0, stream>>>(P, ws, 1);
  group_kernel<__hip_bfloat16><<<NB*NS, 256, 0, stream>>>(d_in[0], d_in[1], d_in[2], ws, 0);
  group_kernel<float><<<NB*NS, 256, 0, stream>>>(d_in[0], d_in[1], d_in[2], ws, 1);
  mlp_kernel<<<NGROUP/2, 256, 0, stream>>>(ws);
  heads_kernel<__hip_bfloat16><<<NGROUP/16, 256, 0, stream>>>(ws, (__hip_bfloat16*)d_out, 0);
  heads_kernel<float><<<NGROUP/16, 256, 0, stream>>>(ws, (float*)d_out, 1);
}